// Round 1
// baseline (119.833 us; speedup 1.0000x reference)
//
#include <hip/hip_runtime.h>
#include <math.h>

constexpr int kMaxF   = 32;
constexpr int kFtOut  = 256;
constexpr int kNumFFT = 640;
constexpr int kNumFT  = 40960;
constexpr int kRowB   = kFtOut;   // fp8: 256 bytes per row

typedef float v2f __attribute__((ext_vector_type(2)));
typedef float v4f __attribute__((ext_vector_type(4)));

__device__ __forceinline__ float clip01(float x) {
    return fminf(fmaxf(x, 0.0f), 1.0f);
}

// ---- prep: one wave per table row ----
// qtab[row][d] = fp8_e4m3(ft_w[row][d] + fft_w[row%640][d]); 4 dims per lane.
// ft_w is streamed once (42.6 MB) -> nontemporal so it doesn't evict qtab from L2.
__global__ __launch_bounds__(256) void prep_fp8_kernel(
    const float* __restrict__ ft_w,
    const float* __restrict__ fft_w,
    unsigned int* __restrict__ qtab,   // 1 dword = 4 fp8 = 4 dims per lane
    int rows)
{
    const int wid  = (blockIdx.x * blockDim.x + threadIdx.x) >> 6;
    const int lane = threadIdx.x & 63;
    if (wid >= rows) return;
    const int d = lane * 4;   // 64 lanes x 4 dims = 256
    const v4f a = __builtin_nontemporal_load(
        reinterpret_cast<const v4f*>(ft_w + (size_t)wid * kFtOut + d));
    const v4f c = *reinterpret_cast<const v4f*>(fft_w + (size_t)(wid % kNumFFT) * kFtOut + d);
    const float w0 = a.x + c.x, w1 = a.y + c.y, w2 = a.z + c.z, w3 = a.w + c.w;

    // byte k of dword = dim d+k (cvt_pk packs src0->byte0, src1->byte1 of word)
    int pk = __builtin_amdgcn_cvt_pk_fp8_f32(w0, w1, 0, false);   // low word
    pk     = __builtin_amdgcn_cvt_pk_fp8_f32(w2, w3, pk, true);   // high word
    qtab[(size_t)wid * (kRowB / 4) + lane] = (unsigned int)pk;
}

// ---- main: one wave per batch element ----
// lane l<32: stm side, dims [8l, 8l+8); lane l>=32: nstm side.
// Indices/values are wave-uniform -> scalar (s_load) path, no shfl.
// Gather address fits 32-bit voffset (idx*256+dbase < 2^24) -> saddr form.
__global__ __launch_bounds__(256) void nnue_fp8_kernel(
    const float* __restrict__ values,
    const int*   __restrict__ stm_idx,
    const int*   __restrict__ nstm_idx,
    const float* __restrict__ ft_b,
    const float* __restrict__ fft_b,
    const unsigned char* __restrict__ qtab,
    const float* __restrict__ out_w,
    const float* __restrict__ out_b,
    float*       __restrict__ out,
    int batch)
{
    const int lane = threadIdx.x & 63;
    // b is wave-uniform; readfirstlane pins it to an SGPR so the idx/value
    // loads below become scalar loads.
    const int b = __builtin_amdgcn_readfirstlane(
        (int)(blockIdx.x * (blockDim.x >> 6)) + ((int)threadIdx.x >> 6));
    if (b >= batch) return;
    const int bo = b * kMaxF;

    const int  dbase = (lane & 31) * 8;   // 8 dims per lane; also byte offset in row
    const bool nside = (lane & 32) != 0;

    v2f acc[4];
    {
        const float4 b0 = *reinterpret_cast<const float4*>(ft_b + dbase);
        const float4 b1 = *reinterpret_cast<const float4*>(ft_b + dbase + 4);
        const float4 c0 = *reinterpret_cast<const float4*>(fft_b + dbase);
        const float4 c1 = *reinterpret_cast<const float4*>(fft_b + dbase + 4);
        acc[0] = v2f{b0.x + c0.x, b0.y + c0.y};
        acc[1] = v2f{b0.z + c0.z, b0.w + c0.w};
        acc[2] = v2f{b1.x + c1.x, b1.y + c1.y};
        acc[3] = v2f{b1.z + c1.z, b1.w + c1.w};
    }

#pragma unroll 16
    for (int f = 0; f < kMaxF; ++f) {
        const int   is = stm_idx[bo + f];    // wave-uniform -> SGPR
        const int   in = nstm_idx[bo + f];   // wave-uniform -> SGPR
        const float v  = values[bo + f];     // wave-uniform -> SGPR
        const int   idx = nside ? in : is;   // one v_cndmask
        // 24-bit offset math: idx*256 + dbase < 2^24
        const unsigned off = (unsigned)idx * 256u + (unsigned)dbase;
        const uint2 raw = *reinterpret_cast<const uint2*>(qtab + off);
        const v2f vv = {v, v};
        acc[0] += vv * __builtin_amdgcn_cvt_pk_f32_fp8((int)raw.x, false);  // dims +0,+1
        acc[1] += vv * __builtin_amdgcn_cvt_pk_f32_fp8((int)raw.x, true);   // dims +2,+3
        acc[2] += vv * __builtin_amdgcn_cvt_pk_f32_fp8((int)raw.y, false);  // dims +4,+5
        acc[3] += vv * __builtin_amdgcn_cvt_pk_f32_fp8((int)raw.y, true);   // dims +6,+7
    }

    // out_w offset: stm lane l -> 8l; nstm lane l -> 256 + 8(l-32) = 8l. Uniform.
    const float4 ow0 = *reinterpret_cast<const float4*>(out_w + 8 * lane);
    const float4 ow1 = *reinterpret_cast<const float4*>(out_w + 8 * lane + 4);

    float p = clip01(acc[0].x) * ow0.x + clip01(acc[0].y) * ow0.y
            + clip01(acc[1].x) * ow0.z + clip01(acc[1].y) * ow0.w
            + clip01(acc[2].x) * ow1.x + clip01(acc[2].y) * ow1.y
            + clip01(acc[3].x) * ow1.z + clip01(acc[3].y) * ow1.w;

#pragma unroll
    for (int off = 32; off > 0; off >>= 1)
        p += __shfl_down(p, off, 64);

    if (lane == 0) {
        const float x = p + out_b[0];
        out[b] = 1.0f / (1.0f + expf(-x));
    }
}

// ---- fallback: direct fp32 gathers (only if ws too small; exact) ----
__device__ __forceinline__ void fma4(float4& acc, float v, const float4& a, const float4& b) {
    acc.x = fmaf(v, a.x + b.x, acc.x);
    acc.y = fmaf(v, a.y + b.y, acc.y);
    acc.z = fmaf(v, a.z + b.z, acc.z);
    acc.w = fmaf(v, a.w + b.w, acc.w);
}

__global__ __launch_bounds__(256) void nnue_halfkp_fallback(
    const float* __restrict__ values,
    const int*   __restrict__ stm_idx,
    const int*   __restrict__ nstm_idx,
    const float* __restrict__ ft_w,
    const float* __restrict__ ft_b,
    const float* __restrict__ fft_w,
    const float* __restrict__ fft_b,
    const float* __restrict__ out_w,
    const float* __restrict__ out_b,
    float*       __restrict__ out,
    int batch)
{
    const int gtid = blockIdx.x * blockDim.x + threadIdx.x;
    const int b    = gtid >> 6;
    const int lane = threadIdx.x & 63;
    if (b >= batch) return;

    float v_reg = 0.0f;
    int   i_reg = 0;
    if (lane < kMaxF) {
        v_reg = values[b * kMaxF + lane];
        i_reg = stm_idx[b * kMaxF + lane];
    } else {
        i_reg = nstm_idx[b * kMaxF + (lane - kMaxF)];
    }

    const float4* ftw4  = reinterpret_cast<const float4*>(ft_w);
    const float4* fftw4 = reinterpret_cast<const float4*>(fft_w);

    const float4 fb  = reinterpret_cast<const float4*>(ft_b)[lane];
    const float4 ffb = reinterpret_cast<const float4*>(fft_b)[lane];
    float4 acc_s = make_float4(fb.x + ffb.x, fb.y + ffb.y, fb.z + ffb.z, fb.w + ffb.w);
    float4 acc_n = acc_s;

#pragma unroll 8
    for (int f = 0; f < kMaxF; ++f) {
        const float v  = __shfl(v_reg, f, 64);
        const int   is = __shfl(i_reg, f, 64);
        const int   in = __shfl(i_reg, f + kMaxF, 64);
        const float4 as = ftw4[is * 64 + lane];
        const float4 bs = fftw4[(is % kNumFFT) * 64 + lane];
        const float4 an = ftw4[in * 64 + lane];
        const float4 bn = fftw4[(in % kNumFFT) * 64 + lane];
        fma4(acc_s, v, as, bs);
        fma4(acc_n, v, an, bn);
    }

    const float4* ow4 = reinterpret_cast<const float4*>(out_w);
    const float4 ws = ow4[lane];
    const float4 wn = ow4[64 + lane];

    float p = clip01(acc_s.x) * ws.x + clip01(acc_s.y) * ws.y
            + clip01(acc_s.z) * ws.z + clip01(acc_s.w) * ws.w
            + clip01(acc_n.x) * wn.x + clip01(acc_n.y) * wn.y
            + clip01(acc_n.z) * wn.z + clip01(acc_n.w) * wn.w;

#pragma unroll
    for (int off = 32; off > 0; off >>= 1)
        p += __shfl_down(p, off, 64);

    if (lane == 0) {
        const float x = p + out_b[0];
        out[b] = 1.0f / (1.0f + expf(-x));
    }
}

extern "C" void kernel_launch(void* const* d_in, const int* in_sizes, int n_in,
                              void* d_out, int out_size, void* d_ws, size_t ws_size,
                              hipStream_t stream) {
    const float* values = (const float*)d_in[0];
    const int*   stm    = (const int*)  d_in[1];
    const int*   nstm   = (const int*)  d_in[2];
    const float* ft_w   = (const float*)d_in[3];
    const float* ft_b   = (const float*)d_in[4];
    const float* fft_w  = (const float*)d_in[5];
    const float* fft_b  = (const float*)d_in[6];
    const float* out_w  = (const float*)d_in[7];
    const float* out_b  = (const float*)d_in[8];
    float* out = (float*)d_out;

    const int batch = in_sizes[0] / kMaxF;   // 8192
    const size_t qtab_bytes = (size_t)kNumFT * kRowB;   // 10.5 MB

    if (ws_size >= qtab_bytes) {
        unsigned char* qtab = (unsigned char*)d_ws;
        const int prep_blocks = (kNumFT * 64 + 255) / 256;
        hipLaunchKernelGGL(prep_fp8_kernel, dim3(prep_blocks), dim3(256), 0, stream,
                           ft_w, fft_w, (unsigned int*)qtab, kNumFT);
        const int blocks = (batch * 64 + 255) / 256;
        hipLaunchKernelGGL(nnue_fp8_kernel, dim3(blocks), dim3(256), 0, stream,
                           values, stm, nstm, ft_b, fft_b, qtab, out_w, out_b, out, batch);
    } else {
        const int blocks = (batch * 64 + 255) / 256;
        hipLaunchKernelGGL(nnue_halfkp_fallback, dim3(blocks), dim3(256), 0, stream,
                           values, stm, nstm, ft_w, ft_b, fft_w, fft_b, out_w, out_b, out, batch);
    }
}

// Round 2
// 113.711 us; speedup vs baseline: 1.0538x; 1.0538x over previous
//
#include <hip/hip_runtime.h>
#include <math.h>

constexpr int kMaxF   = 32;
constexpr int kFtOut  = 256;
constexpr int kNumFFT = 640;
constexpr int kNumFT  = 40960;
constexpr int kRowB   = kFtOut;   // fp8: 256 bytes per row

typedef float v2f __attribute__((ext_vector_type(2)));

__device__ __forceinline__ float clip01(float x) {
    return fminf(fmaxf(x, 0.0f), 1.0f);
}

// ---- prep: one wave per table row ----
// qtab[row][d] = fp8_e4m3(ft_w[row][d] + fft_w[row%640][d]); 4 dims per lane.
__global__ __launch_bounds__(256) void prep_fp8_kernel(
    const float* __restrict__ ft_w,
    const float* __restrict__ fft_w,
    unsigned int* __restrict__ qtab,   // 1 dword = 4 fp8 = 4 dims per lane
    int rows)
{
    const int wid  = (blockIdx.x * blockDim.x + threadIdx.x) >> 6;
    const int lane = threadIdx.x & 63;
    if (wid >= rows) return;
    const int d = lane * 4;   // 64 lanes x 4 dims = 256
    const float4 a = *reinterpret_cast<const float4*>(ft_w + (size_t)wid * kFtOut + d);
    const float4 c = *reinterpret_cast<const float4*>(fft_w + (size_t)(wid % kNumFFT) * kFtOut + d);
    const float w0 = a.x + c.x, w1 = a.y + c.y, w2 = a.z + c.z, w3 = a.w + c.w;

    // byte k of dword = dim d+k (cvt_pk packs src0->byte0, src1->byte1 of word)
    int pk = __builtin_amdgcn_cvt_pk_fp8_f32(w0, w1, 0, false);   // low word
    pk     = __builtin_amdgcn_cvt_pk_fp8_f32(w2, w3, pk, true);   // high word
    qtab[(size_t)wid * (kRowB / 4) + lane] = (unsigned int)pk;
}

// ---- main: one wave per batch element ----
// 16 lanes per row, 16B (dwordx4) per lane, 2 features x 2 sides per iteration:
//   group 0 (lanes  0-15): stm  feature 2t      group 1 (lanes 16-31): stm  feature 2t+1
//   group 2 (lanes 32-47): nstm feature 2t      group 3 (lanes 48-63): nstm feature 2t+1
// Full unroll -> v_readlane with literal lane index (no LDS, no SMEM in loop).
// Even/odd feature partial sums are merged with one lane^16 shuffle pass at the end;
// biases are added in the epilogue (once), so acc starts at zero.
__global__ __launch_bounds__(256) void nnue_fp8_kernel(
    const float* __restrict__ values,
    const int*   __restrict__ stm_idx,
    const int*   __restrict__ nstm_idx,
    const float* __restrict__ ft_b,
    const float* __restrict__ fft_b,
    const unsigned char* __restrict__ qtab,
    const float* __restrict__ out_w,
    const float* __restrict__ out_b,
    float*       __restrict__ out,
    int batch)
{
    const int lane = threadIdx.x & 63;
    const int b    = (int)(blockIdx.x * (blockDim.x >> 6)) + ((int)threadIdx.x >> 6);
    if (b >= batch) return;
    const int bo = b * kMaxF;

    // coalesced preload: lanes [0,32) stm idx + values, lanes [32,64) nstm idx
    float v_reg = 0.0f;
    int   i_reg = 0;
    if (lane < kMaxF) {
        v_reg = values[bo + lane];
        i_reg = stm_idx[bo + lane];
    } else {
        i_reg = nstm_idx[bo + lane - kMaxF];
    }

    const int  sub    = lane & 15;
    const bool oddg   = (lane & 16) != 0;
    const bool nsideb = (lane & 32) != 0;
    const int  dOff   = sub * 16;   // byte offset in row == starting dim (1B/dim)

    v2f acc[8];
#pragma unroll
    for (int i = 0; i < 8; ++i) acc[i] = v2f{0.0f, 0.0f};

#pragma unroll
    for (int t = 0; t < kMaxF / 2; ++t) {
        const int is0 = __builtin_amdgcn_readlane(i_reg, 2 * t);
        const int is1 = __builtin_amdgcn_readlane(i_reg, 2 * t + 1);
        const int in0 = __builtin_amdgcn_readlane(i_reg, 32 + 2 * t);
        const int in1 = __builtin_amdgcn_readlane(i_reg, 33 + 2 * t);
        const float v0 = __uint_as_float(
            __builtin_amdgcn_readlane(__float_as_uint(v_reg), 2 * t));
        const float v1 = __uint_as_float(
            __builtin_amdgcn_readlane(__float_as_uint(v_reg), 2 * t + 1));

        const int   sidx = oddg ? is1 : is0;
        const int   nidx = oddg ? in1 : in0;
        const int   idx  = nsideb ? nidx : sidx;
        const float vf   = oddg ? v1 : v0;

        const unsigned off = (unsigned)idx * 256u + (unsigned)dOff;  // < 2^24
        const uint4 raw = *reinterpret_cast<const uint4*>(qtab + off);

        const v2f vv = {vf, vf};
        acc[0] += vv * __builtin_amdgcn_cvt_pk_f32_fp8((int)raw.x, false);
        acc[1] += vv * __builtin_amdgcn_cvt_pk_f32_fp8((int)raw.x, true);
        acc[2] += vv * __builtin_amdgcn_cvt_pk_f32_fp8((int)raw.y, false);
        acc[3] += vv * __builtin_amdgcn_cvt_pk_f32_fp8((int)raw.y, true);
        acc[4] += vv * __builtin_amdgcn_cvt_pk_f32_fp8((int)raw.z, false);
        acc[5] += vv * __builtin_amdgcn_cvt_pk_f32_fp8((int)raw.z, true);
        acc[6] += vv * __builtin_amdgcn_cvt_pk_f32_fp8((int)raw.w, false);
        acc[7] += vv * __builtin_amdgcn_cvt_pk_f32_fp8((int)raw.w, true);
    }

    // merge even-feature (groups 0,2) and odd-feature (groups 1,3) partials: lane ^ 16
#pragma unroll
    for (int i = 0; i < 8; ++i) {
        acc[i].x += __shfl_xor(acc[i].x, 16, 64);
        acc[i].y += __shfl_xor(acc[i].y, 16, 64);
    }

    // epilogue: bias + clip + dot with out_w over this lane's 16 dims
    const float* owp = out_w + (nsideb ? kFtOut : 0) + dOff;
    float p = 0.0f;
#pragma unroll
    for (int i = 0; i < 4; ++i) {
        const float4 bb = *reinterpret_cast<const float4*>(ft_b  + dOff + 4 * i);
        const float4 cb = *reinterpret_cast<const float4*>(fft_b + dOff + 4 * i);
        const float4 ow = *reinterpret_cast<const float4*>(owp + 4 * i);
        p += clip01(acc[2 * i].x     + bb.x + cb.x) * ow.x;
        p += clip01(acc[2 * i].y     + bb.y + cb.y) * ow.y;
        p += clip01(acc[2 * i + 1].x + bb.z + cb.z) * ow.z;
        p += clip01(acc[2 * i + 1].y + bb.w + cb.w) * ow.w;
    }
    if (oddg) p = 0.0f;   // odd groups duplicate even groups after the merge

#pragma unroll
    for (int off = 32; off > 0; off >>= 1)
        p += __shfl_down(p, off, 64);

    if (lane == 0) {
        const float x = p + out_b[0];
        out[b] = 1.0f / (1.0f + expf(-x));
    }
}

// ---- fallback: direct fp32 gathers (only if ws too small; exact) ----
__device__ __forceinline__ void fma4(float4& acc, float v, const float4& a, const float4& b) {
    acc.x = fmaf(v, a.x + b.x, acc.x);
    acc.y = fmaf(v, a.y + b.y, acc.y);
    acc.z = fmaf(v, a.z + b.z, acc.z);
    acc.w = fmaf(v, a.w + b.w, acc.w);
}

__global__ __launch_bounds__(256) void nnue_halfkp_fallback(
    const float* __restrict__ values,
    const int*   __restrict__ stm_idx,
    const int*   __restrict__ nstm_idx,
    const float* __restrict__ ft_w,
    const float* __restrict__ ft_b,
    const float* __restrict__ fft_w,
    const float* __restrict__ fft_b,
    const float* __restrict__ out_w,
    const float* __restrict__ out_b,
    float*       __restrict__ out,
    int batch)
{
    const int gtid = blockIdx.x * blockDim.x + threadIdx.x;
    const int b    = gtid >> 6;
    const int lane = threadIdx.x & 63;
    if (b >= batch) return;

    float v_reg = 0.0f;
    int   i_reg = 0;
    if (lane < kMaxF) {
        v_reg = values[b * kMaxF + lane];
        i_reg = stm_idx[b * kMaxF + lane];
    } else {
        i_reg = nstm_idx[b * kMaxF + (lane - kMaxF)];
    }

    const float4* ftw4  = reinterpret_cast<const float4*>(ft_w);
    const float4* fftw4 = reinterpret_cast<const float4*>(fft_w);

    const float4 fb  = reinterpret_cast<const float4*>(ft_b)[lane];
    const float4 ffb = reinterpret_cast<const float4*>(fft_b)[lane];
    float4 acc_s = make_float4(fb.x + ffb.x, fb.y + ffb.y, fb.z + ffb.z, fb.w + ffb.w);
    float4 acc_n = acc_s;

#pragma unroll 8
    for (int f = 0; f < kMaxF; ++f) {
        const float v  = __shfl(v_reg, f, 64);
        const int   is = __shfl(i_reg, f, 64);
        const int   in = __shfl(i_reg, f + kMaxF, 64);
        const float4 as = ftw4[is * 64 + lane];
        const float4 bs = fftw4[(is % kNumFFT) * 64 + lane];
        const float4 an = ftw4[in * 64 + lane];
        const float4 bn = fftw4[(in % kNumFFT) * 64 + lane];
        fma4(acc_s, v, as, bs);
        fma4(acc_n, v, an, bn);
    }

    const float4* ow4 = reinterpret_cast<const float4*>(out_w);
    const float4 ws = ow4[lane];
    const float4 wn = ow4[64 + lane];

    float p = clip01(acc_s.x) * ws.x + clip01(acc_s.y) * ws.y
            + clip01(acc_s.z) * ws.z + clip01(acc_s.w) * ws.w
            + clip01(acc_n.x) * wn.x + clip01(acc_n.y) * wn.y
            + clip01(acc_n.z) * wn.z + clip01(acc_n.w) * wn.w;

#pragma unroll
    for (int off = 32; off > 0; off >>= 1)
        p += __shfl_down(p, off, 64);

    if (lane == 0) {
        const float x = p + out_b[0];
        out[b] = 1.0f / (1.0f + expf(-x));
    }
}

extern "C" void kernel_launch(void* const* d_in, const int* in_sizes, int n_in,
                              void* d_out, int out_size, void* d_ws, size_t ws_size,
                              hipStream_t stream) {
    const float* values = (const float*)d_in[0];
    const int*   stm    = (const int*)  d_in[1];
    const int*   nstm   = (const int*)  d_in[2];
    const float* ft_w   = (const float*)d_in[3];
    const float* ft_b   = (const float*)d_in[4];
    const float* fft_w  = (const float*)d_in[5];
    const float* fft_b  = (const float*)d_in[6];
    const float* out_w  = (const float*)d_in[7];
    const float* out_b  = (const float*)d_in[8];
    float* out = (float*)d_out;

    const int batch = in_sizes[0] / kMaxF;   // 8192
    const size_t qtab_bytes = (size_t)kNumFT * kRowB;   // 10.5 MB

    if (ws_size >= qtab_bytes) {
        unsigned char* qtab = (unsigned char*)d_ws;
        const int prep_blocks = (kNumFT * 64 + 255) / 256;
        hipLaunchKernelGGL(prep_fp8_kernel, dim3(prep_blocks), dim3(256), 0, stream,
                           ft_w, fft_w, (unsigned int*)qtab, kNumFT);
        const int blocks = (batch * 64 + 255) / 256;
        hipLaunchKernelGGL(nnue_fp8_kernel, dim3(blocks), dim3(256), 0, stream,
                           values, stm, nstm, ft_b, fft_b, qtab, out_w, out_b, out, batch);
    } else {
        const int blocks = (batch * 64 + 255) / 256;
        hipLaunchKernelGGL(nnue_halfkp_fallback, dim3(blocks), dim3(256), 0, stream,
                           values, stm, nstm, ft_w, ft_b, fft_w, fft_b, out_w, out_b, out, batch);
    }
}